// Round 1
// baseline (3429.049 us; speedup 1.0000x reference)
//
#include <hip/hip_runtime.h>

#define NNODES 10000
#define NEDGES 160000
#define MUL 16
#define EMB 64
#define HID 128

// ---------------------------------------------------------------------------
// Kernel 1: self-connection initializes out (writes every element once).
// out[n, w]        = 0.25 * sum_u nf[n,u]      * sc_w0[u,w]
// out[n, 16+w*3+d] = 0.25 * sum_u nf[n,16+u*3+d] * sc_w1[u,w]
// ---------------------------------------------------------------------------
__global__ __launch_bounds__(256) void selfconn_kernel(
    const float* __restrict__ node_feat,
    const float* __restrict__ sc_w0,
    const float* __restrict__ sc_w1,
    float* __restrict__ out)
{
    const int tid = threadIdx.x;
    const int nl = tid >> 4;          // local node 0..15
    const int wp = tid & 15;          // output w' 0..15
    const int n  = blockIdx.x * 16 + nl;

    __shared__ float nf[16][64];
    __shared__ float w0s[16][16];
    __shared__ float w1s[16][16];

    ((float4*)nf)[tid] = ((const float4*)(node_feat + (size_t)blockIdx.x * 16 * 64))[tid];
    if (tid < 64)       ((float4*)w0s)[tid]      = ((const float4*)sc_w0)[tid];
    else if (tid < 128) ((float4*)w1s)[tid - 64] = ((const float4*)sc_w1)[tid - 64];
    __syncthreads();

    float o0 = 0.f, o1x = 0.f, o1y = 0.f, o1z = 0.f;
#pragma unroll
    for (int u = 0; u < 16; ++u) {
        o0 += nf[nl][u] * w0s[u][wp];
        const float wv = w1s[u][wp];
        o1x += nf[nl][16 + u * 3 + 0] * wv;
        o1y += nf[nl][16 + u * 3 + 1] * wv;
        o1z += nf[nl][16 + u * 3 + 2] * wv;
    }
    float* op = out + (size_t)n * 64;
    op[wp]              = o0  * 0.25f;
    op[16 + wp * 3 + 0] = o1x * 0.25f;
    op[16 + wp * 3 + 1] = o1y * 0.25f;
    op[16 + wp * 3 + 2] = o1z * 0.25f;
}

// ---------------------------------------------------------------------------
// Kernel 2: fused per-edge radial MLP + tensor product + atomic scatter-add.
// 16 edges per 256-thread block; thread = (edge_local, w').
// ---------------------------------------------------------------------------
__global__ __launch_bounds__(256) void edge_kernel(
    const int*   __restrict__ ei,          // (2, E)
    const float* __restrict__ node_feat,   // (N, 64)
    const float* __restrict__ edge_feat,   // (E, 4)
    const float* __restrict__ edge_embed,  // (E, 64)
    const float* __restrict__ w1,          // (64, 128)
    const float* __restrict__ w2,          // (128, 128)
    const float* __restrict__ w3,          // (128, 1280)
    float* __restrict__ out)               // (N, 64)
{
    const int tid = threadIdx.x;
    const int el = tid >> 4;          // local edge 0..15
    const int wp = tid & 15;          // w' 0..15
    const int e0 = blockIdx.x * 16;
    const int e  = e0 + el;

    __shared__ float ee[16][64];      // edge_embed tile; reused as node-feature row
    __shared__ float h1s[16][128];
    __shared__ float h2s[16][128];
    __shared__ float sA[16][16];      // x0*y0
    __shared__ float sB[16][16];      // dot/sqrt3
    __shared__ float sX0[16][16];     // x0
    __shared__ float sP3[16][48];     // x1*y0
    __shared__ float sP4[16][48];     // cross/sqrt2
    __shared__ float sY1[16][3];

    // ---- stage edge_embed tile ----
    ((float4*)ee)[tid] = ((const float4*)(edge_embed + (size_t)e0 * EMB))[tid];
    __syncthreads();

    // ---- h1 = silu(ee @ W1 / sqrt(64)) ----
#pragma unroll
    for (int i = 0; i < 8; ++i) {
        const int c = wp + i * 16;
        float acc = 0.f;
#pragma unroll 4
        for (int k = 0; k < EMB; ++k)
            acc += ee[el][k] * w1[k * HID + c];
        acc *= 0.125f;
        h1s[el][c] = acc / (1.f + __expf(-acc));
    }
    __syncthreads();

    // ---- reload ee as src-node feature row (readers of ee are done) ----
    const int src = ei[e];
    ((float4*)ee)[tid] = ((const float4*)(node_feat + (size_t)src * 64))[wp];

    // ---- h2 = silu(h1 @ W2 / sqrt(128)) ----
#pragma unroll
    for (int i = 0; i < 8; ++i) {
        const int c = wp + i * 16;
        float acc = 0.f;
#pragma unroll 4
        for (int k = 0; k < HID; ++k)
            acc += h1s[el][k] * w2[k * HID + c];
        acc *= 0.08838834764831845f;   // 1/sqrt(128)
        h2s[el][c] = acc / (1.f + __expf(-acc));
    }
    __syncthreads();

    // ---- per-edge tensor-product inputs (thread wp plays role of u) ----
    {
        const int u = wp;
        const float y0  = edge_feat[e * 4 + 0];
        const float y1x = edge_feat[e * 4 + 1];
        const float y1y = edge_feat[e * 4 + 2];
        const float y1z = edge_feat[e * 4 + 3];
        const float x0u = ee[el][u];
        const float xa  = ee[el][16 + u * 3 + 0];
        const float xb  = ee[el][16 + u * 3 + 1];
        const float xc  = ee[el][16 + u * 3 + 2];
        sX0[el][u] = x0u;
        sA[el][u]  = x0u * y0;
        sB[el][u]  = (xa * y1x + xb * y1y + xc * y1z) * 0.5773502691896258f; // /sqrt3
        sP3[el][u * 3 + 0] = xa * y0;
        sP3[el][u * 3 + 1] = xb * y0;
        sP3[el][u * 3 + 2] = xc * y0;
        sP4[el][u * 3 + 0] = (xb * y1z - xc * y1y) * 0.7071067811865476f; // /sqrt2
        sP4[el][u * 3 + 1] = (xc * y1x - xa * y1z) * 0.7071067811865476f;
        sP4[el][u * 3 + 2] = (xa * y1y - xb * y1x) * 0.7071067811865476f;
        if (u == 0) { sY1[el][0] = y1x; sY1[el][1] = y1y; sY1[el][2] = y1z; }
    }
    __syncthreads();

    const float* w3b = w3 + wp;

    // ---- Group A: paths 0,1 (scalar output o0) ----
    float a0[16], a1[16];
#pragma unroll
    for (int u = 0; u < 16; ++u) { a0[u] = 0.f; a1[u] = 0.f; }
#pragma unroll 2
    for (int k = 0; k < HID; ++k) {
        const float hv = h2s[el][k];
        const float* p = w3b + k * 1280;
#pragma unroll
        for (int u = 0; u < 16; ++u) {
            a0[u] += hv * p[u * 16];
            a1[u] += hv * p[256 + u * 16];
        }
    }
    float o0 = 0.f;
#pragma unroll
    for (int u = 0; u < 16; ++u)
        o0 += a0[u] * sA[el][u] + a1[u] * sB[el][u];

    // ---- Group B: paths 2,3,4 (vector output o1) ----
    float b2[16], b3[16], b4[16];
#pragma unroll
    for (int u = 0; u < 16; ++u) { b2[u] = 0.f; b3[u] = 0.f; b4[u] = 0.f; }
#pragma unroll 2
    for (int k = 0; k < HID; ++k) {
        const float hv = h2s[el][k];
        const float* p = w3b + k * 1280;
#pragma unroll
        for (int u = 0; u < 16; ++u) {
            b2[u] += hv * p[512 + u * 16];
            b3[u] += hv * p[768 + u * 16];
            b4[u] += hv * p[1024 + u * 16];
        }
    }
    float s2 = 0.f, o1x = 0.f, o1y = 0.f, o1z = 0.f;
#pragma unroll
    for (int u = 0; u < 16; ++u) {
        s2  += b2[u] * sX0[el][u];
        o1x += b3[u] * sP3[el][u * 3 + 0] + b4[u] * sP4[el][u * 3 + 0];
        o1y += b3[u] * sP3[el][u * 3 + 1] + b4[u] * sP4[el][u * 3 + 1];
        o1z += b3[u] * sP3[el][u * 3 + 2] + b4[u] * sP4[el][u * 3 + 2];
    }
    o1x += s2 * sY1[el][0];
    o1y += s2 * sY1[el][1];
    o1z += s2 * sY1[el][2];

    // fold (1/sqrt(128) for w) * (1/sqrt(MUL)=0.25)
    const float SC = 0.08838834764831845f * 0.25f;
    const int dst = ei[NEDGES + e];
    float* op = out + (size_t)dst * 64;
    atomicAdd(&op[wp],              o0  * SC);
    atomicAdd(&op[16 + wp * 3 + 0], o1x * SC);
    atomicAdd(&op[16 + wp * 3 + 1], o1y * SC);
    atomicAdd(&op[16 + wp * 3 + 2], o1z * SC);
}

extern "C" void kernel_launch(void* const* d_in, const int* in_sizes, int n_in,
                              void* d_out, int out_size, void* d_ws, size_t ws_size,
                              hipStream_t stream) {
    const int*   ei         = (const int*)  d_in[0];
    const float* node_feat  = (const float*)d_in[1];
    const float* edge_feat  = (const float*)d_in[2];
    const float* edge_embed = (const float*)d_in[3];
    const float* fc_w1      = (const float*)d_in[4];
    const float* fc_w2      = (const float*)d_in[5];
    const float* fc_w3      = (const float*)d_in[6];
    const float* sc_w0      = (const float*)d_in[7];
    const float* sc_w1      = (const float*)d_in[8];
    float* out = (float*)d_out;

    selfconn_kernel<<<NNODES / 16, 256, 0, stream>>>(node_feat, sc_w0, sc_w1, out);
    edge_kernel<<<NEDGES / 16, 256, 0, stream>>>(ei, node_feat, edge_feat, edge_embed,
                                                 fc_w1, fc_w2, fc_w3, out);
}

// Round 2
// 157.246 us; speedup vs baseline: 21.8069x; 21.8069x over previous
//
#include <hip/hip_runtime.h>

#define NNODES 10000
#define NEDGES 160000
#define MUL 16
#define EMB 64
#define HID 128

#define RS128 0.08838834764831845f           // 1/sqrt(128)
#define SC3   (0.08838834764831845f * 0.25f) // 1/sqrt(128) * 1/sqrt(MUL)

typedef __attribute__((ext_vector_type(8))) _Float16 half8;
typedef __attribute__((ext_vector_type(4))) _Float16 half4;
typedef __attribute__((ext_vector_type(4))) float f32x4;

// ---------------------------------------------------------------------------
// Self-connection: initializes every element of out (runs first).
// ---------------------------------------------------------------------------
__global__ __launch_bounds__(256) void selfconn_kernel(
    const float* __restrict__ node_feat,
    const float* __restrict__ sc_w0,
    const float* __restrict__ sc_w1,
    float* __restrict__ out)
{
    const int tid = threadIdx.x;
    const int nl = tid >> 4;
    const int wp = tid & 15;
    const int n  = blockIdx.x * 16 + nl;

    __shared__ float nf[16][64];
    __shared__ float w0s[16][16];
    __shared__ float w1s[16][16];

    ((float4*)nf)[tid] = ((const float4*)(node_feat + (size_t)blockIdx.x * 16 * 64))[tid];
    if (tid < 64)       ((float4*)w0s)[tid]      = ((const float4*)sc_w0)[tid];
    else if (tid < 128) ((float4*)w1s)[tid - 64] = ((const float4*)sc_w1)[tid - 64];
    __syncthreads();

    float o0 = 0.f, o1x = 0.f, o1y = 0.f, o1z = 0.f;
#pragma unroll
    for (int u = 0; u < 16; ++u) {
        o0 += nf[nl][u] * w0s[u][wp];
        const float wv = w1s[u][wp];
        o1x += nf[nl][16 + u * 3 + 0] * wv;
        o1y += nf[nl][16 + u * 3 + 1] * wv;
        o1z += nf[nl][16 + u * 3 + 2] * wv;
    }
    float* op = out + (size_t)n * 64;
    op[wp]              = o0  * 0.25f;
    op[16 + wp * 3 + 0] = o1x * 0.25f;
    op[16 + wp * 3 + 1] = o1y * 0.25f;
    op[16 + wp * 3 + 2] = o1z * 0.25f;
}

// ---------------------------------------------------------------------------
// Prep: pack fc weights as fp16 in MFMA B-fragment order, scales folded in.
// Fragment layout for 16x16x32: lane l holds B[k=(l>>4)*8+j][n=l&15], j=0..7.
// half-index = ((nt*KS + ks)*64 + lane)*8 + j
//   w1p: 8 nt x 2 ks  -> [0, 8192)
//   w2p: 8 nt x 4 ks  -> [8192, 24576)
//   w3p: 80 nt x 4 ks -> [24576, 188416)
// ---------------------------------------------------------------------------
__global__ __launch_bounds__(256) void prep_kernel(
    const float* __restrict__ w1,
    const float* __restrict__ w2,
    const float* __restrict__ w3,
    _Float16* __restrict__ wp)
{
    int idx = blockIdx.x * 256 + threadIdx.x;
    if (idx < 8192) {
        int j = idx & 7, lane = (idx >> 3) & 63, ks = (idx >> 9) & 1, nt = idx >> 10;
        int k = ks * 32 + (lane >> 4) * 8 + j;
        int n = nt * 16 + (lane & 15);
        wp[idx] = (_Float16)(w1[k * HID + n] * 0.125f);
    } else if (idx < 24576) {
        int t = idx - 8192;
        int j = t & 7, lane = (t >> 3) & 63, ks = (t >> 9) & 3, nt = t >> 11;
        int k = ks * 32 + (lane >> 4) * 8 + j;
        int n = nt * 16 + (lane & 15);
        wp[idx] = (_Float16)(w2[k * HID + n] * RS128);
    } else if (idx < 188416) {
        int t = idx - 24576;
        int j = t & 7, lane = (t >> 3) & 63, ks = (t >> 9) & 3, nt = t >> 11;
        int k = ks * 32 + (lane >> 4) * 8 + j;
        int n = nt * 16 + (lane & 15);
        wp[idx] = (_Float16)(w3[k * 1280 + n] * SC3);
    }
}

// ---------------------------------------------------------------------------
// Main fused kernel: 32 edges / block, 4 waves (wm = M-group, wn = N-half).
// ---------------------------------------------------------------------------
__global__ __launch_bounds__(256, 3) void edge_mfma_kernel(
    const int*   __restrict__ ei,
    const float* __restrict__ node_feat,
    const float* __restrict__ edge_feat,
    const float* __restrict__ edge_embed,
    const _Float16* __restrict__ wpk,
    float* __restrict__ out)
{
    const int tid = threadIdx.x;
    const int e0  = blockIdx.x * 32;

    __shared__ __align__(16) char eeRaw[32 * 128];   // ee fp16, swizzled 128B rows
    __shared__ __align__(16) char h1Raw[32 * 256];   // h1 fp16 swizzled / aliases xg f32
    __shared__ __align__(16) char h2Raw[32 * 256];   // h2 fp16 swizzled
    __shared__ float sA [32][17];
    __shared__ float sB [32][17];
    __shared__ float sX0[32][17];
    __shared__ float sP3[32][49];
    __shared__ float sP4[32][49];
    __shared__ float sY1[32][5];
    __shared__ float opart[32][48];
    __shared__ float sEF[32][4];
    __shared__ int   sidx[64];                        // src[0:32], dst[32:64]

    // ---- phase 0: indices + edge_feat ----
    if (tid < 32)       sidx[tid] = ei[e0 + tid];
    else if (tid < 64)  sidx[tid] = ei[NEDGES + e0 + (tid - 32)];
    else if (tid < 192) {
        int t = tid - 64;                 // 0..127
        sEF[t >> 2][t & 3] = edge_feat[(e0 + (t >> 2)) * 4 + (t & 3)];
    }
    __syncthreads();

    // ---- phase 1: stage edge_embed (fp16, swizzled) + gather node rows ----
    float* xg = (float*)h1Raw;            // [32][64] fp32 (aliases h1s)
    {
        const float4* eesrc = (const float4*)(edge_embed + (size_t)e0 * EMB);
#pragma unroll
        for (int it = 0; it < 2; ++it) {
            int f = tid + it * 256;       // 0..511
            int row = f >> 4, c4 = f & 15;
            float4 v = eesrc[f];
            half4 h = { (_Float16)v.x, (_Float16)v.y, (_Float16)v.z, (_Float16)v.w };
            *(half4*)(eeRaw + row * 128 + ((c4 * 8) ^ ((row & 7) << 4))) = h;

            int src = sidx[row];
            float4 nv = ((const float4*)(node_feat + (size_t)src * 64))[c4];
            ((float4*)(xg + row * 64))[c4] = nv;
        }
    }
    __syncthreads();

    // ---- phase 2: per-edge tensor-product t-vectors (fp32) ----
#pragma unroll
    for (int it = 0; it < 2; ++it) {
        int el = (tid >> 4) + it * 16;    // 0..31
        int u  = tid & 15;
        const float* xr = xg + el * 64;
        float x0u = xr[u];
        float xa  = xr[16 + u * 3 + 0];
        float xb  = xr[16 + u * 3 + 1];
        float xc  = xr[16 + u * 3 + 2];
        float y0  = sEF[el][0];
        float y1x = sEF[el][1];
        float y1y = sEF[el][2];
        float y1z = sEF[el][3];
        sX0[el][u] = x0u;
        sA [el][u] = x0u * y0;
        sB [el][u] = (xa * y1x + xb * y1y + xc * y1z) * 0.5773502691896258f;
        sP3[el][u * 3 + 0] = xa * y0;
        sP3[el][u * 3 + 1] = xb * y0;
        sP3[el][u * 3 + 2] = xc * y0;
        sP4[el][u * 3 + 0] = (xb * y1z - xc * y1y) * 0.7071067811865476f;
        sP4[el][u * 3 + 1] = (xc * y1x - xa * y1z) * 0.7071067811865476f;
        sP4[el][u * 3 + 2] = (xa * y1y - xb * y1x) * 0.7071067811865476f;
        if (u == 0) { sY1[el][0] = y1x; sY1[el][1] = y1y; sY1[el][2] = y1z; }
    }
    __syncthreads();   // xg reads done; h1Raw reusable. ee + t-arrays ready.

    const int lane  = tid & 63;
    const int w     = tid >> 6;
    const int wm    = w & 1;
    const int wn    = w >> 1;
    const int arow  = wm * 16 + (lane & 15);
    const int aswz  = (arow & 7) << 4;
    const int ako2  = ((lane >> 4) * 8) * 2;          // byte offset of k in 32-block
    const int crow0 = wm * 16 + (lane >> 4) * 4;      // C-frag row base (edge local)
    const int ccol  = lane & 15;

    const half8* w1p8 = (const half8*)wpk;
    const half8* w2p8 = (const half8*)(wpk + 8192);
    const half8* w3p8 = (const half8*)(wpk + 24576);
    _Float16* h1s = (_Float16*)h1Raw;
    _Float16* h2s = (_Float16*)h2Raw;

    // ---- GEMM1: h1 = silu(ee @ w1p) ----
    {
        half8 a0 = *(const half8*)(eeRaw + arow * 128 + ((ako2     ) ^ aswz));
        half8 a1 = *(const half8*)(eeRaw + arow * 128 + ((64 + ako2) ^ aswz));
#pragma unroll
        for (int i = 0; i < 4; ++i) {
            int nt = wn * 4 + i;
            f32x4 c = {0.f, 0.f, 0.f, 0.f};
            c = __builtin_amdgcn_mfma_f32_16x16x32_f16(a0, w1p8[(nt * 2 + 0) * 64 + lane], c, 0, 0, 0);
            c = __builtin_amdgcn_mfma_f32_16x16x32_f16(a1, w1p8[(nt * 2 + 1) * 64 + lane], c, 0, 0, 0);
#pragma unroll
            for (int r = 0; r < 4; ++r) {
                int row = crow0 + r;
                int col = nt * 16 + ccol;
                float x = c[r];
                float s = x / (1.f + __expf(-x));
                *(_Float16*)(h1Raw + row * 256 + ((col * 2) ^ ((row & 7) << 4))) = (_Float16)s;
            }
        }
    }
    __syncthreads();

    // ---- GEMM2: h2 = silu(h1 @ w2p) ----
    {
        half8 a2[4];
#pragma unroll
        for (int ks = 0; ks < 4; ++ks)
            a2[ks] = *(const half8*)(h1Raw + arow * 256 + ((ks * 64 + ako2) ^ aswz));
#pragma unroll
        for (int i = 0; i < 4; ++i) {
            int nt = wn * 4 + i;
            f32x4 c = {0.f, 0.f, 0.f, 0.f};
#pragma unroll
            for (int ks = 0; ks < 4; ++ks)
                c = __builtin_amdgcn_mfma_f32_16x16x32_f16(a2[ks], w2p8[(nt * 4 + ks) * 64 + lane], c, 0, 0, 0);
#pragma unroll
            for (int r = 0; r < 4; ++r) {
                int row = crow0 + r;
                int col = nt * 16 + ccol;
                float x = c[r];
                float s = x / (1.f + __expf(-x));
                *(_Float16*)(h2Raw + row * 256 + ((col * 2) ^ ((row & 7) << 4))) = (_Float16)s;
            }
        }
    }
    __syncthreads();

    // ---- Big GEMM: w-tiles (fixed p,u per 16-col tile) x immediate contraction ----
    half8 a3[4];
#pragma unroll
    for (int ks = 0; ks < 4; ++ks)
        a3[ks] = *(const half8*)(h2Raw + arow * 256 + ((ks * 64 + ako2) ^ aswz));

    float acc0[4] = {0.f, 0.f, 0.f, 0.f};
    float acc1[4][3] = {{0.f,0.f,0.f},{0.f,0.f,0.f},{0.f,0.f,0.f},{0.f,0.f,0.f}};

#define MM_TILE(NT, C)                                                          \
    { const half8* bp = w3p8 + ((NT) * 4) * 64 + lane;                          \
      C = __builtin_amdgcn_mfma_f32_16x16x32_f16(a3[0], bp[0],   C, 0, 0, 0);   \
      C = __builtin_amdgcn_mfma_f32_16x16x32_f16(a3[1], bp[64],  C, 0, 0, 0);   \
      C = __builtin_amdgcn_mfma_f32_16x16x32_f16(a3[2], bp[128], C, 0, 0, 0);   \
      C = __builtin_amdgcn_mfma_f32_16x16x32_f16(a3[3], bp[192], C, 0, 0, 0); }

    if (wn == 0) {
#pragma unroll 4
        for (int u = 0; u < 16; ++u) {              // p=0 tiles 0..15
            f32x4 c = {0.f, 0.f, 0.f, 0.f};
            MM_TILE(u, c);
#pragma unroll
            for (int r = 0; r < 4; ++r) acc0[r] += c[r] * sA[crow0 + r][u];
        }
#pragma unroll 4
        for (int u = 0; u < 16; ++u) {              // p=1 tiles 16..31
            f32x4 c = {0.f, 0.f, 0.f, 0.f};
            MM_TILE(16 + u, c);
#pragma unroll
            for (int r = 0; r < 4; ++r) acc0[r] += c[r] * sB[crow0 + r][u];
        }
#pragma unroll 4
        for (int u = 0; u < 8; ++u) {               // p=2 tiles 32..39 (u 0..7)
            f32x4 c = {0.f, 0.f, 0.f, 0.f};
            MM_TILE(32 + u, c);
#pragma unroll
            for (int r = 0; r < 4; ++r) {
                float t = c[r] * sX0[crow0 + r][u];
#pragma unroll
                for (int d = 0; d < 3; ++d) acc1[r][d] += t * sY1[crow0 + r][d];
            }
        }
    } else {
#pragma unroll 4
        for (int u = 8; u < 16; ++u) {              // p=2 tiles 40..47 (u 8..15)
            f32x4 c = {0.f, 0.f, 0.f, 0.f};
            MM_TILE(32 + u, c);
#pragma unroll
            for (int r = 0; r < 4; ++r) {
                float t = c[r] * sX0[crow0 + r][u];
#pragma unroll
                for (int d = 0; d < 3; ++d) acc1[r][d] += t * sY1[crow0 + r][d];
            }
        }
#pragma unroll 4
        for (int u = 0; u < 16; ++u) {              // p=3 tiles 48..63
            f32x4 c = {0.f, 0.f, 0.f, 0.f};
            MM_TILE(48 + u, c);
#pragma unroll
            for (int r = 0; r < 4; ++r)
#pragma unroll
                for (int d = 0; d < 3; ++d) acc1[r][d] += c[r] * sP3[crow0 + r][u * 3 + d];
        }
#pragma unroll 4
        for (int u = 0; u < 16; ++u) {              // p=4 tiles 64..79
            f32x4 c = {0.f, 0.f, 0.f, 0.f};
            MM_TILE(64 + u, c);
#pragma unroll
            for (int r = 0; r < 4; ++r)
#pragma unroll
                for (int d = 0; d < 3; ++d) acc1[r][d] += c[r] * sP4[crow0 + r][u * 3 + d];
        }
    }
#undef MM_TILE

    // ---- combine o1 halves via LDS, then atomics (64 adds / edge total) ----
    if (wn == 0) {
#pragma unroll
        for (int r = 0; r < 4; ++r)
#pragma unroll
            for (int d = 0; d < 3; ++d)
                opart[crow0 + r][ccol * 3 + d] = acc1[r][d];
    }
    __syncthreads();

    if (wn == 0) {
#pragma unroll
        for (int r = 0; r < 4; ++r) {
            int el = crow0 + r;
            int dst = sidx[32 + el];
            atomicAdd(&out[(size_t)dst * 64 + ccol], acc0[r]);
        }
    } else {
#pragma unroll
        for (int r = 0; r < 4; ++r) {
            int el = crow0 + r;
            int dst = sidx[32 + el];
#pragma unroll
            for (int d = 0; d < 3; ++d)
                atomicAdd(&out[(size_t)dst * 64 + 16 + ccol * 3 + d],
                          acc1[r][d] + opart[el][ccol * 3 + d]);
        }
    }
}

extern "C" void kernel_launch(void* const* d_in, const int* in_sizes, int n_in,
                              void* d_out, int out_size, void* d_ws, size_t ws_size,
                              hipStream_t stream) {
    const int*   ei         = (const int*)  d_in[0];
    const float* node_feat  = (const float*)d_in[1];
    const float* edge_feat  = (const float*)d_in[2];
    const float* edge_embed = (const float*)d_in[3];
    const float* fc_w1      = (const float*)d_in[4];
    const float* fc_w2      = (const float*)d_in[5];
    const float* fc_w3      = (const float*)d_in[6];
    const float* sc_w0      = (const float*)d_in[7];
    const float* sc_w1      = (const float*)d_in[8];
    float* out = (float*)d_out;
    _Float16* wpk = (_Float16*)d_ws;   // 188416 halves = 368 KB

    prep_kernel<<<736, 256, 0, stream>>>(fc_w1, fc_w2, fc_w3, wpk);
    selfconn_kernel<<<NNODES / 16, 256, 0, stream>>>(node_feat, sc_w0, sc_w1, out);
    edge_mfma_kernel<<<NEDGES / 32, 256, 0, stream>>>(ei, node_feat, edge_feat, edge_embed,
                                                      wpk, out);
}

// Round 3
// 149.014 us; speedup vs baseline: 23.0116x; 1.0552x over previous
//
#include <hip/hip_runtime.h>

#define NNODES 10000
#define NEDGES 160000
#define MUL 16
#define EMB 64
#define HID 128

#define RS128 0.08838834764831845f           // 1/sqrt(128)
#define SC3   (0.08838834764831845f * 0.25f) // 1/sqrt(128) * 1/sqrt(MUL)

typedef __attribute__((ext_vector_type(8))) _Float16 half8;
typedef __attribute__((ext_vector_type(4))) _Float16 half4;
typedef __attribute__((ext_vector_type(4))) float f32x4;

// ---------------------------------------------------------------------------
// Self-connection: initializes every element of out (runs first).
// ---------------------------------------------------------------------------
__global__ __launch_bounds__(256) void selfconn_kernel(
    const float* __restrict__ node_feat,
    const float* __restrict__ sc_w0,
    const float* __restrict__ sc_w1,
    float* __restrict__ out)
{
    const int tid = threadIdx.x;
    const int nl = tid >> 4;
    const int wp = tid & 15;
    const int n  = blockIdx.x * 16 + nl;

    __shared__ float nf[16][64];
    __shared__ float w0s[16][16];
    __shared__ float w1s[16][16];

    ((float4*)nf)[tid] = ((const float4*)(node_feat + (size_t)blockIdx.x * 16 * 64))[tid];
    if (tid < 64)       ((float4*)w0s)[tid]      = ((const float4*)sc_w0)[tid];
    else if (tid < 128) ((float4*)w1s)[tid - 64] = ((const float4*)sc_w1)[tid - 64];
    __syncthreads();

    float o0 = 0.f, o1x = 0.f, o1y = 0.f, o1z = 0.f;
#pragma unroll
    for (int u = 0; u < 16; ++u) {
        o0 += nf[nl][u] * w0s[u][wp];
        const float wv = w1s[u][wp];
        o1x += nf[nl][16 + u * 3 + 0] * wv;
        o1y += nf[nl][16 + u * 3 + 1] * wv;
        o1z += nf[nl][16 + u * 3 + 2] * wv;
    }
    float* op = out + (size_t)n * 64;
    op[wp]              = o0  * 0.25f;
    op[16 + wp * 3 + 0] = o1x * 0.25f;
    op[16 + wp * 3 + 1] = o1y * 0.25f;
    op[16 + wp * 3 + 2] = o1z * 0.25f;
}

// ---------------------------------------------------------------------------
// Prep: pack fc weights as fp16 in MFMA B-fragment order, scales folded in.
// half-index = ((nt*KS + ks)*64 + lane)*8 + j ; B[k=ks*32+(lane>>4)*8+j][n=nt*16+(lane&15)]
//   w1p: 8 nt x 2 ks  -> [0, 8192)
//   w2p: 8 nt x 4 ks  -> [8192, 24576)
//   w3p: 80 nt x 4 ks -> [24576, 188416)
// ---------------------------------------------------------------------------
__global__ __launch_bounds__(256) void prep_kernel(
    const float* __restrict__ w1,
    const float* __restrict__ w2,
    const float* __restrict__ w3,
    _Float16* __restrict__ wp)
{
    int idx = blockIdx.x * 256 + threadIdx.x;
    if (idx < 8192) {
        int j = idx & 7, lane = (idx >> 3) & 63, ks = (idx >> 9) & 1, nt = idx >> 10;
        int k = ks * 32 + (lane >> 4) * 8 + j;
        int n = nt * 16 + (lane & 15);
        wp[idx] = (_Float16)(w1[k * HID + n] * 0.125f);
    } else if (idx < 24576) {
        int t = idx - 8192;
        int j = t & 7, lane = (t >> 3) & 63, ks = (t >> 9) & 3, nt = t >> 11;
        int k = ks * 32 + (lane >> 4) * 8 + j;
        int n = nt * 16 + (lane & 15);
        wp[idx] = (_Float16)(w2[k * HID + n] * RS128);
    } else if (idx < 188416) {
        int t = idx - 24576;
        int j = t & 7, lane = (t >> 3) & 63, ks = (t >> 9) & 3, nt = t >> 11;
        int k = ks * 32 + (lane >> 4) * 8 + j;
        int n = nt * 16 + (lane & 15);
        wp[idx] = (_Float16)(w3[k * 1280 + n] * SC3);
    }
}

// ---------------------------------------------------------------------------
// LDS layout (bytes):
//   [0,4096)      eeRaw (fp16 swizzled)     | aliased later by opart
//   [4096,12288)  h1 (fp16 swz) / xg (f32)  | aliased later by opart
//   [12288,20480) h2 (fp16 swz)             | aliased later by opart
//   [20480,22528) sA_T  [16][32] f32        | aliased later by opart
//   [22528,24576) sB_T  [16][32]            | aliased later by opart
//   [24576,26624) sX_T  [16][32]            | aliased later by opart
//   [26624,32768) sP3_T [16][96]            | aliased later by opart
//   [32768,38912) sP4_T [16][96]            |  (opart = 4 x 32 x 65 f32 = 33280 B)
//   [38912,39296) sY_T  [3][32]
//   [39296,39808) sEF   [32][4]
//   [39808,40064) sidx  [64] int
// ---------------------------------------------------------------------------
#define EE_OFF   0
#define H1_OFF   4096
#define H2_OFF   12288
#define SA_OFF   20480
#define SB_OFF   22528
#define SX_OFF   24576
#define SP3_OFF  26624
#define SP4_OFF  32768
#define SY_OFF   38912
#define SEF_OFF  39296
#define SIDX_OFF 39808
#define SMEM_BYTES 40064
#define OPW 65   // opart row stride (floats), breaks row*64 bank aliasing

__global__ __launch_bounds__(256, 4) void edge_mfma_kernel(
    const int*   __restrict__ ei,
    const float* __restrict__ node_feat,
    const float* __restrict__ edge_feat,
    const float* __restrict__ edge_embed,
    const _Float16* __restrict__ wpk,
    float* __restrict__ out)
{
    __shared__ __align__(16) char smem[SMEM_BYTES];

    const int tid = threadIdx.x;
    const int e0  = blockIdx.x * 32;

    int*   sidxp = (int*)(smem + SIDX_OFF);
    float* sEFp  = (float*)(smem + SEF_OFF);

    // ---- phase 0: indices + edge_feat ----
    if (tid < 32)       sidxp[tid] = ei[e0 + tid];
    else if (tid < 64)  sidxp[tid] = ei[NEDGES + e0 + (tid - 32)];
    else if (tid < 192) {
        int t = tid - 64;                 // 0..127
        sEFp[t] = edge_feat[e0 * 4 + t];
    }
    __syncthreads();

    // ---- phase 1: stage edge_embed (fp16, swizzled) + gather node rows ----
    float* xg = (float*)(smem + H1_OFF);  // [32][64] f32 (aliases h1)
    {
        const float4* eesrc = (const float4*)(edge_embed + (size_t)e0 * EMB);
#pragma unroll
        for (int it = 0; it < 2; ++it) {
            int f = tid + it * 256;       // 0..511
            int row = f >> 4, c4 = f & 15;
            float4 v = eesrc[f];
            half4 h = { (_Float16)v.x, (_Float16)v.y, (_Float16)v.z, (_Float16)v.w };
            *(half4*)(smem + EE_OFF + row * 128 + ((c4 * 8) ^ ((row & 7) << 4))) = h;

            int src = sidxp[row];
            float4 nv = ((const float4*)(node_feat + (size_t)src * 64))[c4];
            ((float4*)(xg + row * 64))[c4] = nv;
        }
    }
    __syncthreads();

    // ---- phase 2: per-edge t-vectors, TRANSPOSED layouts ----
    {
        float* sAT  = (float*)(smem + SA_OFF);
        float* sBT  = (float*)(smem + SB_OFF);
        float* sXT  = (float*)(smem + SX_OFF);
        float* sP3T = (float*)(smem + SP3_OFF);
        float* sP4T = (float*)(smem + SP4_OFF);
        float* sYT  = (float*)(smem + SY_OFF);
#pragma unroll
        for (int it = 0; it < 2; ++it) {
            int el = (tid >> 4) + it * 16;    // 0..31
            int u  = tid & 15;
            const float* xr = xg + el * 64;
            float x0u = xr[u];
            float xa  = xr[16 + u * 3 + 0];
            float xb  = xr[16 + u * 3 + 1];
            float xc  = xr[16 + u * 3 + 2];
            float y0  = sEFp[el * 4 + 0];
            float y1x = sEFp[el * 4 + 1];
            float y1y = sEFp[el * 4 + 2];
            float y1z = sEFp[el * 4 + 3];
            sXT[u * 32 + el] = x0u;
            sAT[u * 32 + el] = x0u * y0;
            sBT[u * 32 + el] = (xa * y1x + xb * y1y + xc * y1z) * 0.5773502691896258f;
            sP3T[u * 96 + el * 3 + 0] = xa * y0;
            sP3T[u * 96 + el * 3 + 1] = xb * y0;
            sP3T[u * 96 + el * 3 + 2] = xc * y0;
            sP4T[u * 96 + el * 3 + 0] = (xb * y1z - xc * y1y) * 0.7071067811865476f;
            sP4T[u * 96 + el * 3 + 1] = (xc * y1x - xa * y1z) * 0.7071067811865476f;
            sP4T[u * 96 + el * 3 + 2] = (xa * y1y - xb * y1x) * 0.7071067811865476f;
            if (u < 3) sYT[u * 32 + el] = sEFp[el * 4 + 1 + u];
        }
    }
    __syncthreads();   // xg dead; h1 region reusable

    const int lane  = tid & 63;
    const int w     = tid >> 6;
    const int wm    = w & 1;           // GEMM1/2 role
    const int wn    = w >> 1;          // GEMM1/2 role
    const int aswz  = (lane & 7) << 4;
    const int ako2  = (lane >> 4) * 16;          // byte offset of k-group
    const int ccol  = lane & 15;
    const int crow00 = (lane >> 4) * 4;          // C row base within 16-tile

    const half8* w1p8 = (const half8*)wpk;
    const half8* w2p8 = (const half8*)(wpk + 8192);
    const half8* w3p8 = (const half8*)(wpk + 24576);

    // ---- GEMM1: h1 = silu(ee @ w1p) ----
    {
        const int arow = wm * 16 + (lane & 15);
        half8 a0 = *(const half8*)(smem + EE_OFF + arow * 128 + ((ako2     ) ^ aswz));
        half8 a1 = *(const half8*)(smem + EE_OFF + arow * 128 + ((64 + ako2) ^ aswz));
        const int crow0 = wm * 16 + crow00;
#pragma unroll
        for (int i = 0; i < 4; ++i) {
            int nt = wn * 4 + i;
            f32x4 c = {0.f, 0.f, 0.f, 0.f};
            c = __builtin_amdgcn_mfma_f32_16x16x32_f16(a0, w1p8[(nt * 2 + 0) * 64 + lane], c, 0, 0, 0);
            c = __builtin_amdgcn_mfma_f32_16x16x32_f16(a1, w1p8[(nt * 2 + 1) * 64 + lane], c, 0, 0, 0);
#pragma unroll
            for (int r = 0; r < 4; ++r) {
                int row = crow0 + r;
                int col = nt * 16 + ccol;
                float x = c[r];
                float s = x / (1.f + __expf(-x));
                *(_Float16*)(smem + H1_OFF + row * 256 + ((col * 2) ^ ((row & 7) << 4))) = (_Float16)s;
            }
        }
    }
    __syncthreads();

    // ---- GEMM2: h2 = silu(h1 @ w2p) ----
    {
        const int arow = wm * 16 + (lane & 15);
        half8 a2[4];
#pragma unroll
        for (int ks = 0; ks < 4; ++ks)
            a2[ks] = *(const half8*)(smem + H1_OFF + arow * 256 + ((ks * 64 + ako2) ^ aswz));
        const int crow0 = wm * 16 + crow00;
#pragma unroll
        for (int i = 0; i < 4; ++i) {
            int nt = wn * 4 + i;
            f32x4 c = {0.f, 0.f, 0.f, 0.f};
#pragma unroll
            for (int ks = 0; ks < 4; ++ks)
                c = __builtin_amdgcn_mfma_f32_16x16x32_f16(a2[ks], w2p8[(nt * 4 + ks) * 64 + lane], c, 0, 0, 0);
#pragma unroll
            for (int r = 0; r < 4; ++r) {
                int row = crow0 + r;
                int col = nt * 16 + ccol;
                float x = c[r];
                float s = x / (1.f + __expf(-x));
                *(_Float16*)(smem + H2_OFF + row * 256 + ((col * 2) ^ ((row & 7) << 4))) = (_Float16)s;
            }
        }
    }
    __syncthreads();

    // ---- Big GEMM: each wave covers BOTH 16-edge M-tiles for 20 nt tiles ----
    half8 a3[2][4];
#pragma unroll
    for (int m = 0; m < 2; ++m) {
        const int arow = m * 16 + (lane & 15);
#pragma unroll
        for (int ks = 0; ks < 4; ++ks)
            a3[m][ks] = *(const half8*)(smem + H2_OFF + arow * 256 + ((ks * 64 + ako2) ^ aswz));
    }

    float acc0[2][4] = {{0,0,0,0},{0,0,0,0}};
    float s2  [2][4] = {{0,0,0,0},{0,0,0,0}};
    float acc1[2][4][3] = {};

#define MM8(NT, C0, C1) { \
    const half8* bp = w3p8 + (size_t)(NT) * 256 + lane; \
    half8 b0 = bp[0], b1 = bp[64], b2 = bp[128], b3 = bp[192]; \
    C0 = __builtin_amdgcn_mfma_f32_16x16x32_f16(a3[0][0], b0, C0, 0, 0, 0); \
    C1 = __builtin_amdgcn_mfma_f32_16x16x32_f16(a3[1][0], b0, C1, 0, 0, 0); \
    C0 = __builtin_amdgcn_mfma_f32_16x16x32_f16(a3[0][1], b1, C0, 0, 0, 0); \
    C1 = __builtin_amdgcn_mfma_f32_16x16x32_f16(a3[1][1], b1, C1, 0, 0, 0); \
    C0 = __builtin_amdgcn_mfma_f32_16x16x32_f16(a3[0][2], b2, C0, 0, 0, 0); \
    C1 = __builtin_amdgcn_mfma_f32_16x16x32_f16(a3[1][2], b2, C1, 0, 0, 0); \
    C0 = __builtin_amdgcn_mfma_f32_16x16x32_f16(a3[0][3], b3, C0, 0, 0, 0); \
    C1 = __builtin_amdgcn_mfma_f32_16x16x32_f16(a3[1][3], b3, C1, 0, 0, 0); }

#define EPI_T(U, TOFF, ACC) { \
    float4 t0 = *(const float4*)(smem + (TOFF) + (U) * 128 + crow00 * 4); \
    float4 t1 = *(const float4*)(smem + (TOFF) + (U) * 128 + crow00 * 4 + 64); \
    ACC[0][0] += c0[0] * t0.x; ACC[0][1] += c0[1] * t0.y; \
    ACC[0][2] += c0[2] * t0.z; ACC[0][3] += c0[3] * t0.w; \
    ACC[1][0] += c1[0] * t1.x; ACC[1][1] += c1[1] * t1.y; \
    ACC[1][2] += c1[2] * t1.z; ACC[1][3] += c1[3] * t1.w; }

#define EPI_V(U, TOFF) { \
    const char* tb = smem + (TOFF) + (U) * 384 + crow00 * 12; \
    float4 q0 = *(const float4*)(tb);      \
    float4 q1 = *(const float4*)(tb + 16); \
    float4 q2 = *(const float4*)(tb + 32); \
    acc1[0][0][0] += c0[0]*q0.x; acc1[0][0][1] += c0[0]*q0.y; acc1[0][0][2] += c0[0]*q0.z; \
    acc1[0][1][0] += c0[1]*q0.w; acc1[0][1][1] += c0[1]*q1.x; acc1[0][1][2] += c0[1]*q1.y; \
    acc1[0][2][0] += c0[2]*q1.z; acc1[0][2][1] += c0[2]*q1.w; acc1[0][2][2] += c0[2]*q2.x; \
    acc1[0][3][0] += c0[3]*q2.y; acc1[0][3][1] += c0[3]*q2.z; acc1[0][3][2] += c0[3]*q2.w; \
    float4 p0 = *(const float4*)(tb + 192); \
    float4 p1 = *(const float4*)(tb + 208); \
    float4 p2 = *(const float4*)(tb + 224); \
    acc1[1][0][0] += c1[0]*p0.x; acc1[1][0][1] += c1[0]*p0.y; acc1[1][0][2] += c1[0]*p0.z; \
    acc1[1][1][0] += c1[1]*p0.w; acc1[1][1][1] += c1[1]*p1.x; acc1[1][1][2] += c1[1]*p1.y; \
    acc1[1][2][0] += c1[2]*p1.z; acc1[1][2][1] += c1[2]*p1.w; acc1[1][2][2] += c1[2]*p2.x; \
    acc1[1][3][0] += c1[3]*p2.y; acc1[1][3][1] += c1[3]*p2.z; acc1[1][3][2] += c1[3]*p2.w; }

#define TILE_T(NT, U, TOFF, ACC) { \
    f32x4 c0 = {0.f,0.f,0.f,0.f}, c1 = {0.f,0.f,0.f,0.f}; \
    MM8(NT, c0, c1); EPI_T(U, TOFF, ACC); }

#define TILE_V(NT, U, TOFF) { \
    f32x4 c0 = {0.f,0.f,0.f,0.f}, c1 = {0.f,0.f,0.f,0.f}; \
    MM8(NT, c0, c1); EPI_V(U, TOFF); }

    switch (w) {
    case 0:
#pragma unroll 4
        for (int u = 0; u < 16; ++u) TILE_T(u, u, SA_OFF, acc0);
#pragma unroll
        for (int u = 0; u < 4; ++u)  TILE_T(16 + u, u, SB_OFF, acc0);
        break;
    case 1:
#pragma unroll 4
        for (int u = 4; u < 16; ++u) TILE_T(16 + u, u, SB_OFF, acc0);
#pragma unroll 4
        for (int u = 0; u < 8; ++u)  TILE_T(32 + u, u, SX_OFF, s2);
        break;
    case 2:
#pragma unroll 4
        for (int u = 8; u < 16; ++u) TILE_T(32 + u, u, SX_OFF, s2);
#pragma unroll 4
        for (int u = 0; u < 12; ++u) TILE_V(48 + u, u, SP3_OFF);
        break;
    default:
#pragma unroll
        for (int u = 12; u < 16; ++u) TILE_V(48 + u, u, SP3_OFF);
#pragma unroll 4
        for (int u = 0; u < 16; ++u)  TILE_V(64 + u, u, SP4_OFF);
        break;
    }
#undef MM8
#undef EPI_T
#undef EPI_V
#undef TILE_T
#undef TILE_V

    // ---- fold s2 (path 2) with y1 ----
#pragma unroll
    for (int m = 0; m < 2; ++m) {
        const char* yb = smem + SY_OFF + crow00 * 4 + m * 64;
        float4 yx = *(const float4*)(yb);
        float4 yy = *(const float4*)(yb + 128);
        float4 yz = *(const float4*)(yb + 256);
        acc1[m][0][0] += s2[m][0] * yx.x; acc1[m][0][1] += s2[m][0] * yy.x; acc1[m][0][2] += s2[m][0] * yz.x;
        acc1[m][1][0] += s2[m][1] * yx.y; acc1[m][1][1] += s2[m][1] * yy.y; acc1[m][1][2] += s2[m][1] * yz.y;
        acc1[m][2][0] += s2[m][2] * yx.z; acc1[m][2][1] += s2[m][2] * yy.z; acc1[m][2][2] += s2[m][2] * yz.z;
        acc1[m][3][0] += s2[m][3] * yx.w; acc1[m][3][1] += s2[m][3] * yy.w; acc1[m][3][2] += s2[m][3] * yz.w;
    }

    // ---- cross-wave reduce through LDS (opart aliases [0, 33280)) ----
    __syncthreads();   // all waves done reading h2 / t-arrays

    {
        float* myop = (float*)smem + w * 32 * OPW;
#pragma unroll
        for (int m = 0; m < 2; ++m)
#pragma unroll
            for (int r = 0; r < 4; ++r) {
                int row = crow00 + m * 16 + r;
                float* rp = myop + row * OPW;
                rp[ccol]                 = acc0[m][r];
                rp[16 + ccol * 3 + 0]    = acc1[m][r][0];
                rp[16 + ccol * 3 + 1]    = acc1[m][r][1];
                rp[16 + ccol * 3 + 2]    = acc1[m][r][2];
            }
    }
    __syncthreads();

    {
        const float* opf = (const float*)smem;
        const int rloc = lane >> 4;
#pragma unroll
        for (int rr = 0; rr < 2; ++rr) {
            int row = w * 8 + rr * 4 + rloc;
            int dst = sidxp[32 + row];
            float* op = out + (size_t)dst * 64;
            float v = opf[0 * 32 * OPW + row * OPW + ccol]
                    + opf[1 * 32 * OPW + row * OPW + ccol]
                    + opf[2 * 32 * OPW + row * OPW + ccol]
                    + opf[3 * 32 * OPW + row * OPW + ccol];
            atomicAdd(op + ccol, v);
#pragma unroll
            for (int d = 0; d < 3; ++d) {
                int c = 16 + ccol * 3 + d;
                float v1 = opf[0 * 32 * OPW + row * OPW + c]
                         + opf[1 * 32 * OPW + row * OPW + c]
                         + opf[2 * 32 * OPW + row * OPW + c]
                         + opf[3 * 32 * OPW + row * OPW + c];
                atomicAdd(op + c, v1);
            }
        }
    }
}

extern "C" void kernel_launch(void* const* d_in, const int* in_sizes, int n_in,
                              void* d_out, int out_size, void* d_ws, size_t ws_size,
                              hipStream_t stream) {
    const int*   ei         = (const int*)  d_in[0];
    const float* node_feat  = (const float*)d_in[1];
    const float* edge_feat  = (const float*)d_in[2];
    const float* edge_embed = (const float*)d_in[3];
    const float* fc_w1      = (const float*)d_in[4];
    const float* fc_w2      = (const float*)d_in[5];
    const float* fc_w3      = (const float*)d_in[6];
    const float* sc_w0      = (const float*)d_in[7];
    const float* sc_w1      = (const float*)d_in[8];
    float* out = (float*)d_out;
    _Float16* wpk = (_Float16*)d_ws;   // 188416 halves = 368 KB

    prep_kernel<<<736, 256, 0, stream>>>(fc_w1, fc_w2, fc_w3, wpk);
    selfconn_kernel<<<NNODES / 16, 256, 0, stream>>>(node_feat, sc_w0, sc_w1, out);
    edge_mfma_kernel<<<NEDGES / 32, 256, 0, stream>>>(ei, node_feat, edge_feat, edge_embed,
                                                      wpk, out);
}